// Round 1
// baseline (267.506 us; speedup 1.0000x reference)
//
#include <hip/hip_runtime.h>
#include <math.h>

// DecodeSBP: x[1,133,512,512] fp32 -> per-keypoint argmax of sigmoid heatmap,
// conf-thresholded joints [133,3] = (x*4, y*4, conf) or (-4,-4,-1).
//
// sigmoid is strictly monotone => argmax(sigmoid(x)) == argmax(x).
// Single fused kernel: raw-x argmax streaming (nontemporal float4, 3 VALU/elem),
// cross-block merge via packed u64 atomicMax (ordered-float-bits | ~idx),
// last-arriving block per row decodes + sigmoids the single winner.
//
// Roofline note: input = 139.5 MB read once = ~22 us at 6.3 TB/s. The other
// ~162 us of the measured total is the harness's 2x558MB poison fills (81 us
// each, seen in rocprof) -- not controllable here. This version removes the
// phase-2 dispatch + inter-kernel dependency (~5-7 us).

#define KPTS     133
#define WW       512
#define HW       (512 * 512)        // 262144 elements per keypoint row
#define NCHUNK   16                 // chunks per row (blocks per row)
#define CHUNK    (HW / NCHUNK)      // 16384 elements
#define NTHREADS 256
#define V4_PER_T (CHUNK / 4 / NTHREADS)  // 16 float4 loads per thread

// clang native vector — accepted by __builtin_nontemporal_load
typedef float floatx4 __attribute__((ext_vector_type(4)));

// (val, idx) argmax with first-index tie-break (matches jnp.argmax).
__device__ __forceinline__ void red(float& bv, unsigned& bi, float v, unsigned i) {
    if (v > bv || (v == bv && i < bi)) { bv = v; bi = i; }
}

// Monotone float -> u32 map: a > b  <=>  ord_bits(a) > ord_bits(b) (finite floats).
// All finite floats map to > 0, so a zeroed amax slot is the identity for max.
__device__ __forceinline__ unsigned ord_bits(float f) {
    const unsigned u = __float_as_uint(f);
    return (u & 0x80000000u) ? ~u : (u | 0x80000000u);
}

__global__ __launch_bounds__(NTHREADS)
void k_fused(const float* __restrict__ x,
             unsigned long long* __restrict__ amax,   // [KPTS], zeroed
             unsigned* __restrict__ cnt,              // [KPTS], zeroed
             float* __restrict__ out) {
    const int b = blockIdx.x;
    const int k = b / NCHUNK;          // keypoint row
    const int c = b % NCHUNK;          // chunk within row
    const int t = threadIdx.x;

    const floatx4* src = reinterpret_cast<const floatx4*>(
        x + (size_t)k * HW + (size_t)c * CHUNK);
    const unsigned base = (unsigned)(c * CHUNK);

    float bv = -3.402823466e+38f;
    unsigned bi = 0u;

    // 16 independent nontemporal float4 loads per thread; coalesced:
    // wave reads 1 KB/instr. Compiler batches them in vmcnt groups.
#pragma unroll
    for (int i = 0; i < V4_PER_T; ++i) {
        const int e = t + i * NTHREADS;
        const floatx4 v = __builtin_nontemporal_load(&src[e]);
        const unsigned idx = base + (unsigned)e * 4u;
        // quad argmax, first-index on ties (>= keeps the earlier element)
        const float    m01 = fmaxf(v.x, v.y);
        const unsigned i01 = (v.x >= v.y) ? idx : idx + 1u;
        const float    m23 = fmaxf(v.z, v.w);
        const unsigned i23 = (v.z >= v.w) ? idx + 2u : idx + 3u;
        const float    m   = fmaxf(m01, m23);
        const unsigned im  = (m01 >= m23) ? i01 : i23;
        // within a thread idx strictly increases, so '>' keeps first index
        if (m > bv) { bv = m; bi = im; }
    }

    // wave64 shuffle reduction (full tie check: indices interleave across lanes)
    for (int off = 32; off > 0; off >>= 1) {
        const float    ov = __shfl_down(bv, off, 64);
        const unsigned oi = __shfl_down(bi, off, 64);
        red(bv, bi, ov, oi);
    }

    __shared__ float    sv[NTHREADS / 64];
    __shared__ unsigned si[NTHREADS / 64];
    const int lane = t & 63, wid = t >> 6;
    if (lane == 0) { sv[wid] = bv; si[wid] = bi; }
    __syncthreads();

    if (t == 0) {
        for (int w = 1; w < NTHREADS / 64; ++w) red(bv, bi, sv[w], si[w]);

        // Pack (val, idx): key compare == (val, -idx) lexicographic compare,
        // so atomicMax == argmax with first-index tie-break across chunks.
        const unsigned long long key =
            ((unsigned long long)ord_bits(bv) << 32) | (unsigned long long)(~bi);
        __hip_atomic_fetch_max(&amax[k], key, __ATOMIC_RELEASE,
                               __HIP_MEMORY_SCOPE_AGENT);

        // Arrival counter: RMW chain on cnt[k] is a release sequence, so the
        // 16th arriver's acquire makes all prior fetch_max results visible
        // (valid across XCDs at agent scope).
        const unsigned prev = __hip_atomic_fetch_add(&cnt[k], 1u, __ATOMIC_ACQ_REL,
                                                     __HIP_MEMORY_SCOPE_AGENT);
        if (prev == NCHUNK - 1) {
            const unsigned long long fin =
                __hip_atomic_load(&amax[k], __ATOMIC_ACQUIRE,
                                  __HIP_MEMORY_SCOPE_AGENT);
            const unsigned ob   = (unsigned)(fin >> 32);
            const unsigned bits = (ob & 0x80000000u) ? (ob ^ 0x80000000u) : ~ob;
            const float    val  = __uint_as_float(bits);
            const unsigned idx  = ~(unsigned)(fin & 0xFFFFFFFFull);

            const float conf = 1.0f / (1.0f + expf(-val));   // sigmoid, winner only
            const bool valid = conf > 0.8f;                  // CONF_THRESHOLD
            const float scale = 4.0f;                        // INPUT_SIZE/W = 2048/512
            out[k * 3 + 0] = valid ? (float)(idx % WW) * scale : -scale;
            out[k * 3 + 1] = valid ? (float)(idx / WW) * scale : -scale;
            out[k * 3 + 2] = valid ? conf : -1.0f;
        }
    }
}

extern "C" void kernel_launch(void* const* d_in, const int* in_sizes, int n_in,
                              void* d_out, int out_size, void* d_ws, size_t ws_size,
                              hipStream_t stream) {
    const float* x = (const float*)d_in[0];
    float* out = (float*)d_out;

    // workspace: amax[133] u64 + cnt[133] u32 = 1596 B (ws is poisoned each
    // iteration -> must re-zero; hipMemsetAsync is graph-capturable).
    unsigned long long* amax = (unsigned long long*)d_ws;
    unsigned* cnt = (unsigned*)((char*)d_ws + KPTS * sizeof(unsigned long long));

    hipMemsetAsync(d_ws, 0,
                   KPTS * (sizeof(unsigned long long) + sizeof(unsigned)), stream);
    k_fused<<<KPTS * NCHUNK, NTHREADS, 0, stream>>>(x, amax, cnt, out);
}

// Round 2
// 203.840 us; speedup vs baseline: 1.3123x; 1.3123x over previous
//
#include <hip/hip_runtime.h>
#include <math.h>

// DecodeSBP: x[1,133,512,512] fp32 -> per-keypoint argmax of sigmoid heatmap,
// conf-thresholded joints [133,3] = (x*4, y*4, conf) or (-4,-4,-1).
//
// sigmoid is strictly monotone => argmax(sigmoid(x)) == argmax(x).
//
// Round-1 post-mortem: fusing via agent-scope atomics (RELEASE/ACQ_REL) put a
// cache-invalidate + vmcnt(0) storm in every block tail -> the 25us stream
// became 118us (564 GB/s, 7% peak). Cross-block merge atomics are poison here.
//
// This version: ONE block of 1024 threads (16 waves) per keypoint row.
// Grid = 133 blocks -> one per CU. No atomics, no workspace, no memset,
// one dispatch. Per-CU demand to saturate HBM: 6.3TB/s / 133 = 47 GB/s;
// 16 waves x 8-deep unrolled dwordx4 nt-loads = 128 KB in flight per CU
// (need ~18 KB at ~900cy latency) -> HBM-bound, ~22-30 us kernel.

#define KPTS     133
#define WW       512
#define HW       (512 * 512)            // 262144 elements per keypoint row
#define NTHREADS 1024                   // 16 waves, one block per row
#define NWAVES   (NTHREADS / 64)
#define V4_PER_T (HW / 4 / NTHREADS)    // 64 float4 loads per thread

// clang native vector — accepted by __builtin_nontemporal_load
// (HIP_vector_type float4 is a struct and is rejected).
typedef float floatx4 __attribute__((ext_vector_type(4)));

// (val, idx) argmax with first-index tie-break (matches jnp.argmax).
__device__ __forceinline__ void red(float& bv, unsigned& bi, float v, unsigned i) {
    if (v > bv || (v == bv && i < bi)) { bv = v; bi = i; }
}

__global__ __launch_bounds__(NTHREADS)
void k_rowmax(const float* __restrict__ x, float* __restrict__ out) {
    const int k = blockIdx.x;              // keypoint row (one block per row)
    const int t = threadIdx.x;

    const floatx4* src = reinterpret_cast<const floatx4*>(x + (size_t)k * HW);

    float bv = -3.402823466e+38f;
    unsigned bi = 0u;

    // 64 coalesced nontemporal float4 loads per thread, 8-deep unroll for MLP.
    // Wave reads 1 KB/instr; per-thread idx strictly increases with i, so the
    // '>' accept keeps the first index on ties.
#pragma unroll 8
    for (int i = 0; i < V4_PER_T; ++i) {
        const int e = t + i * NTHREADS;
        const floatx4 v = __builtin_nontemporal_load(&src[e]);
        const unsigned idx = (unsigned)e * 4u;
        // quad argmax, first-index on ties (>= keeps the earlier element)
        const float    m01 = fmaxf(v.x, v.y);
        const unsigned i01 = (v.x >= v.y) ? idx : idx + 1u;
        const float    m23 = fmaxf(v.z, v.w);
        const unsigned i23 = (v.z >= v.w) ? idx + 2u : idx + 3u;
        const float    m   = fmaxf(m01, m23);
        const unsigned im  = (m01 >= m23) ? i01 : i23;
        if (m > bv) { bv = m; bi = im; }
    }

    // wave64 shuffle reduction (indices interleave across lanes: full tie check)
    for (int off = 32; off > 0; off >>= 1) {
        const float    ov = __shfl_down(bv, off, 64);
        const unsigned oi = __shfl_down(bi, off, 64);
        red(bv, bi, ov, oi);
    }

    __shared__ float    sv[NWAVES];
    __shared__ unsigned si[NWAVES];
    const int lane = t & 63, wid = t >> 6;
    if (lane == 0) { sv[wid] = bv; si[wid] = bi; }
    __syncthreads();

    if (t == 0) {
        // merge 16 wave partials (once per block; serial is fine)
        for (int w = 1; w < NWAVES; ++w) red(bv, bi, sv[w], si[w]);

        const float conf = 1.0f / (1.0f + expf(-bv));   // sigmoid on winner only
        const bool valid = conf > 0.8f;                 // CONF_THRESHOLD
        const float scale = 4.0f;                       // INPUT_SIZE / W = 2048/512
        out[k * 3 + 0] = valid ? (float)(bi % WW) * scale : -scale;
        out[k * 3 + 1] = valid ? (float)(bi / WW) * scale : -scale;
        out[k * 3 + 2] = valid ? conf : -1.0f;
    }
}

extern "C" void kernel_launch(void* const* d_in, const int* in_sizes, int n_in,
                              void* d_out, int out_size, void* d_ws, size_t ws_size,
                              hipStream_t stream) {
    const float* x = (const float*)d_in[0];
    float* out = (float*)d_out;
    k_rowmax<<<KPTS, NTHREADS, 0, stream>>>(x, out);
}

// Round 3
// 192.250 us; speedup vs baseline: 1.3915x; 1.0603x over previous
//
#include <hip/hip_runtime.h>
#include <math.h>

// DecodeSBP: x[1,133,512,512] fp32 -> per-keypoint argmax of sigmoid heatmap,
// conf-thresholded joints [133,3] = (x*4, y*4, conf) or (-4,-4,-1).
//
// sigmoid is strictly monotone => argmax(sigmoid(x)) == argmax(x).
//
// Structure (proven round-0 geometry): 2128 blocks (133 rows x 16 chunks) of
// 256 threads -> full 256-CU coverage -> ~6 TB/s read stream (~23 us). A tiny
// second kernel merges 16 packed u64 partials per row. No atomics (round 1
// showed agent-scope acquire/release = cache-invalidate storm, 4.7x slowdown),
// and NOT one-block-per-row (round 2 showed 133 CUs cap at ~3.7 TB/s: per-CU
// streaming is issue-rate-limited at ~28 GB/s).
//
// Floor arithmetic: 2x83us harness poison fills (fixed) + 139.5MB/6.3TBps
// = ~22us read + ~4us phase2/launch => ~190-193 us total.

#define KPTS     133
#define WW       512
#define HW       (512 * 512)        // 262144 elements per keypoint row
#define NCHUNK   16                 // chunks per row (phase-1 blocks per row)
#define CHUNK    (HW / NCHUNK)      // 16384 elements
#define NTHREADS 256
#define V4_PER_T (CHUNK / 4 / NTHREADS)  // 16 float4 loads per thread

// clang native vector — accepted by __builtin_nontemporal_load
typedef float floatx4 __attribute__((ext_vector_type(4)));

// (val, idx) argmax with first-index tie-break (matches jnp.argmax).
__device__ __forceinline__ void red(float& bv, unsigned& bi, float v, unsigned i) {
    if (v > bv || (v == bv && i < bi)) { bv = v; bi = i; }
}

// Monotone float -> u32 (finite floats): a > b <=> ord_bits(a) > ord_bits(b).
__device__ __forceinline__ unsigned ord_bits(float f) {
    const unsigned u = __float_as_uint(f);
    return (u & 0x80000000u) ? ~u : (u | 0x80000000u);
}

__global__ __launch_bounds__(NTHREADS)
void k_phase1(const float* __restrict__ x, unsigned long long* __restrict__ pp) {
    const int b = blockIdx.x;
    const int k = b / NCHUNK;          // keypoint row
    const int c = b % NCHUNK;          // chunk within row
    const int t = threadIdx.x;

    const floatx4* src = reinterpret_cast<const floatx4*>(
        x + (size_t)k * HW + (size_t)c * CHUNK);
    const unsigned base = (unsigned)(c * CHUNK);

    float bv = -3.402823466e+38f;
    unsigned bi = 0u;

    // 16 independent nontemporal float4 loads per thread; coalesced:
    // wave reads 1 KB/instr; compiler stages them in vmcnt batches.
#pragma unroll
    for (int i = 0; i < V4_PER_T; ++i) {
        const int e = t + i * NTHREADS;
        const floatx4 v = __builtin_nontemporal_load(&src[e]);
        const unsigned idx = base + (unsigned)e * 4u;
        // quad argmax, first-index on ties (>= keeps the earlier element)
        const float    m01 = fmaxf(v.x, v.y);
        const unsigned i01 = (v.x >= v.y) ? idx : idx + 1u;
        const float    m23 = fmaxf(v.z, v.w);
        const unsigned i23 = (v.z >= v.w) ? idx + 2u : idx + 3u;
        const float    m   = fmaxf(m01, m23);
        const unsigned im  = (m01 >= m23) ? i01 : i23;
        // within a thread idx strictly increases, so '>' keeps first index
        if (m > bv) { bv = m; bi = im; }
    }

    // wave64 shuffle reduction (indices interleave across lanes: full tie check)
    for (int off = 32; off > 0; off >>= 1) {
        const float    ov = __shfl_down(bv, off, 64);
        const unsigned oi = __shfl_down(bi, off, 64);
        red(bv, bi, ov, oi);
    }

    __shared__ float    sv[NTHREADS / 64];
    __shared__ unsigned si[NTHREADS / 64];
    const int lane = t & 63, wid = t >> 6;
    if (lane == 0) { sv[wid] = bv; si[wid] = bi; }
    __syncthreads();
    if (t == 0) {
        for (int w = 1; w < NTHREADS / 64; ++w) red(bv, bi, sv[w], si[w]);
        // Packed key: lexicographic (val, -idx) -> plain u64 max in phase 2
        // is argmax with first-index tie-break. Single 8B store.
        pp[b] = ((unsigned long long)ord_bits(bv) << 32)
              | (unsigned long long)(~bi);
    }
}

__global__ __launch_bounds__(64)
void k_phase2(const unsigned long long* __restrict__ pp,
              float* __restrict__ out) {
    const int k = blockIdx.x;
    const int t = threadIdx.x;

    // identity 0: every finite float's key has a nonzero high word
    unsigned long long key = 0ull;
    if (t < NCHUNK) key = pp[k * NCHUNK + t];

    for (int off = 8; off > 0; off >>= 1) {
        const unsigned long long o = __shfl_down(key, off, 64);
        if (o > key) key = o;
    }

    if (t == 0) {
        const unsigned ob   = (unsigned)(key >> 32);
        const unsigned bits = (ob & 0x80000000u) ? (ob ^ 0x80000000u) : ~ob;
        const float    val  = __uint_as_float(bits);
        const unsigned idx  = ~(unsigned)(key & 0xFFFFFFFFull);

        const float conf = 1.0f / (1.0f + expf(-val));   // sigmoid, winner only
        const bool valid = conf > 0.8f;                  // CONF_THRESHOLD
        const float scale = 4.0f;                        // INPUT_SIZE/W = 2048/512
        out[k * 3 + 0] = valid ? (float)(idx % WW) * scale : -scale;
        out[k * 3 + 1] = valid ? (float)(idx / WW) * scale : -scale;
        out[k * 3 + 2] = valid ? conf : -1.0f;
    }
}

extern "C" void kernel_launch(void* const* d_in, const int* in_sizes, int n_in,
                              void* d_out, int out_size, void* d_ws, size_t ws_size,
                              hipStream_t stream) {
    const float* x = (const float*)d_in[0];
    float* out = (float*)d_out;

    // workspace: packed (val,idx) key per (row, chunk) — 133*16*8 B = 17 KB
    unsigned long long* pp = (unsigned long long*)d_ws;

    k_phase1<<<KPTS * NCHUNK, NTHREADS, 0, stream>>>(x, pp);
    k_phase2<<<KPTS, 64, 0, stream>>>(pp, out);
}